// Round 9
// baseline (32.756 us; speedup 1.0000x reference)
//
#include <hip/hip_runtime.h>

#define LD4(p) (*reinterpret_cast<const float4*>(p))
typedef __attribute__((ext_vector_type(8))) unsigned short ushort8_t;

__device__ __forceinline__ unsigned short f2bf(float x) {   // RNE
    unsigned u = __float_as_uint(x);
    return (unsigned short)((u + 0x7fffu + ((u >> 16) & 1u)) >> 16);
}
__device__ __forceinline__ float bf2f(unsigned short s) {
    return __uint_as_float((unsigned)s << 16);
}

__global__ __launch_bounds__(256) void fc_conv(
    const float* __restrict__ fc, unsigned short* __restrict__ dst, int n8)
{
    const int tid = blockIdx.x * blockDim.x + threadIdx.x;
    const int nth = gridDim.x * blockDim.x;
    for (int j = tid; j < n8; j += nth) {
        const float4 a = LD4(fc + (size_t)j * 8);
        const float4 b = LD4(fc + (size_t)j * 8 + 4);
        ushort8_t o;
        o[0] = f2bf(a.x); o[1] = f2bf(a.y); o[2] = f2bf(a.z); o[3] = f2bf(a.w);
        o[4] = f2bf(b.x); o[5] = f2bf(b.y); o[6] = f2bf(b.z); o[7] = f2bf(b.w);
        *reinterpret_cast<ushort8_t*>(dst + (size_t)j * 8) = o;
    }
}

__device__ __forceinline__ float dot8(float4 ea, float4 eb, ushort8_t w) {
    return ea.x*bf2f(w[0]) + ea.y*bf2f(w[1]) + ea.z*bf2f(w[2]) + ea.w*bf2f(w[3])
         + eb.x*bf2f(w[4]) + eb.y*bf2f(w[5]) + eb.z*bf2f(w[6]) + eb.w*bf2f(w[7]);
}

__device__ __forceinline__ float red16(float q) {
    q += __shfl_xor(q, 1, 16);
    q += __shfl_xor(q, 2, 16);
    q += __shfl_xor(q, 4, 16);
    q += __shfl_xor(q, 8, 16);
    return q;
}

__device__ __forceinline__ float bce_term(float q, float y, float m) {
    return m * (fmaxf(q, 0.0f) - q * y + __logf(1.0f + __expf(-fabsf(q))));
}

// bf16-gather main: one wave per row, 4 groups split the path (R8 structure).
__global__ __launch_bounds__(256) void hs_main_bf(
    const float* __restrict__ emb,
    const unsigned short* __restrict__ fcb,   // [V-1, 256] bf16
    const int*   __restrict__ target,
    const int*   __restrict__ path_idx,
    const float* __restrict__ path_codes,
    const float* __restrict__ path_mask,
    float2* __restrict__ partials,
    int N, int L)
{
    const int lane = threadIdx.x & 63;
    const int g    = lane >> 4;
    const int li   = lane & 15;
    const int wid  = threadIdx.x >> 6;
    const int gwave  = blockIdx.x * (blockDim.x >> 6) + wid;
    const int nwaves = gridDim.x * (blockDim.x >> 6);

    float bce_acc = 0.0f;
    float cnt_acc = 0.0f;

    for (int row = gwave; row < N; row += nwaves) {
        const float* erow = emb + (size_t)row * 256 + li * 16;
        const float4 e0 = LD4(erow), e1 = LD4(erow + 4),
                     e2 = LD4(erow + 8), e3 = LD4(erow + 12);
        const int t = target[row];

        int pi = 0; float pc = 0.0f, pm = 0.0f;
        if (lane < L) {
            const size_t off = (size_t)t * L + lane;
            pi = path_idx[off];
            pc = path_codes[off];
            pm = path_mask[off];
        }
        const unsigned long long bal = __ballot(pm != 0.0f);
        const int plen = __popcll(bal);
        cnt_acc += (float)plen;

        for (int j4 = 0; j4 < plen; j4 += 8) {
            const int i0 = j4 + g;
            const int i1 = j4 + 4 + g;
            const int n0 = __shfl(pi, i0, 64);
            const int n1 = __shfl(pi, i1, 64);
            const unsigned short* p0 = fcb + ((size_t)n0 << 8) + li * 16;
            const unsigned short* p1 = fcb + ((size_t)n1 << 8) + li * 16;
            // 4 independent 16B loads: 8 cache lines per visit (vs 16 in fp32)
            const ushort8_t wa0 = *reinterpret_cast<const ushort8_t*>(p0);
            const ushort8_t wa1 = *reinterpret_cast<const ushort8_t*>(p0 + 8);
            const ushort8_t wb0 = *reinterpret_cast<const ushort8_t*>(p1);
            const ushort8_t wb1 = *reinterpret_cast<const ushort8_t*>(p1 + 8);
            const float y0 = __shfl(pc, i0, 64);
            const float y1 = __shfl(pc, i1, 64);
            const float m0 = (i0 < plen) ? 1.0f : 0.0f;
            const float m1 = (i1 < plen) ? 1.0f : 0.0f;

            float q0 = dot8(e0, e1, wa0) + dot8(e2, e3, wa1);
            float q1 = dot8(e0, e1, wb0) + dot8(e2, e3, wb1);
            q0 = red16(q0);
            q1 = red16(q1);

            bce_acc += bce_term(q0, y0, m0);
            bce_acc += bce_term(q1, y1, m1);
        }
    }

    bce_acc += __shfl_xor(bce_acc, 16, 64);
    bce_acc += __shfl_xor(bce_acc, 32, 64);

    __shared__ float s_b[4], s_c[4];
    if (lane == 0) { s_b[wid] = bce_acc; s_c[wid] = cnt_acc; }
    __syncthreads();
    if (threadIdx.x == 0) {
        const int nw = blockDim.x >> 6;
        float b = 0.0f, c = 0.0f;
        for (int i = 0; i < nw; ++i) { b += s_b[i]; c += s_c[i]; }
        partials[blockIdx.x] = make_float2(b, c);
    }
}

// fp32 fallback (R8 main) if workspace can't hold the bf16 table
__global__ __launch_bounds__(256) void hs_main_f32(
    const float* __restrict__ emb,
    const float* __restrict__ fc,
    const int*   __restrict__ target,
    const int*   __restrict__ path_idx,
    const float* __restrict__ path_codes,
    const float* __restrict__ path_mask,
    float2* __restrict__ partials,
    int N, int L)
{
    const int lane = threadIdx.x & 63;
    const int g    = lane >> 4;
    const int li   = lane & 15;
    const int wid  = threadIdx.x >> 6;
    const int gwave  = blockIdx.x * (blockDim.x >> 6) + wid;
    const int nwaves = gridDim.x * (blockDim.x >> 6);

    float bce_acc = 0.0f, cnt_acc = 0.0f;

    for (int row = gwave; row < N; row += nwaves) {
        const float* erow = emb + (size_t)row * 256 + li * 16;
        const float4 e0 = LD4(erow), e1 = LD4(erow + 4),
                     e2 = LD4(erow + 8), e3 = LD4(erow + 12);
        const int t = target[row];

        int pi = 0; float pc = 0.0f, pm = 0.0f;
        if (lane < L) {
            const size_t off = (size_t)t * L + lane;
            pi = path_idx[off];
            pc = path_codes[off];
            pm = path_mask[off];
        }
        const unsigned long long bal = __ballot(pm != 0.0f);
        const int plen = __popcll(bal);
        cnt_acc += (float)plen;

        for (int j4 = 0; j4 < plen; j4 += 8) {
            const int i0 = j4 + g;
            const int i1 = j4 + 4 + g;
            const int n0 = __shfl(pi, i0, 64);
            const int n1 = __shfl(pi, i1, 64);
            const float* p0 = fc + ((size_t)n0 << 8) + li * 16;
            const float* p1 = fc + ((size_t)n1 << 8) + li * 16;
            const float4 a0 = LD4(p0), a1 = LD4(p0 + 4), a2 = LD4(p0 + 8), a3 = LD4(p0 + 12);
            const float4 b0 = LD4(p1), b1 = LD4(p1 + 4), b2 = LD4(p1 + 8), b3 = LD4(p1 + 12);
            const float y0 = __shfl(pc, i0, 64);
            const float y1 = __shfl(pc, i1, 64);
            const float m0 = (i0 < plen) ? 1.0f : 0.0f;
            const float m1 = (i1 < plen) ? 1.0f : 0.0f;

            float q0 = a0.x*e0.x+a0.y*e0.y+a0.z*e0.z+a0.w*e0.w
                     + a1.x*e1.x+a1.y*e1.y+a1.z*e1.z+a1.w*e1.w
                     + a2.x*e2.x+a2.y*e2.y+a2.z*e2.z+a2.w*e2.w
                     + a3.x*e3.x+a3.y*e3.y+a3.z*e3.z+a3.w*e3.w;
            float q1 = b0.x*e0.x+b0.y*e0.y+b0.z*e0.z+b0.w*e0.w
                     + b1.x*e1.x+b1.y*e1.y+b1.z*e1.z+b1.w*e1.w
                     + b2.x*e2.x+b2.y*e2.y+b2.z*e2.z+b2.w*e2.w
                     + b3.x*e3.x+b3.y*e3.y+b3.z*e3.z+b3.w*e3.w;
            q0 = red16(q0);
            q1 = red16(q1);
            bce_acc += bce_term(q0, y0, m0);
            bce_acc += bce_term(q1, y1, m1);
        }
    }

    bce_acc += __shfl_xor(bce_acc, 16, 64);
    bce_acc += __shfl_xor(bce_acc, 32, 64);

    __shared__ float s_b[4], s_c[4];
    if (lane == 0) { s_b[wid] = bce_acc; s_c[wid] = cnt_acc; }
    __syncthreads();
    if (threadIdx.x == 0) {
        const int nw = blockDim.x >> 6;
        float b = 0.0f, c = 0.0f;
        for (int i = 0; i < nw; ++i) { b += s_b[i]; c += s_c[i]; }
        partials[blockIdx.x] = make_float2(b, c);
    }
}

__global__ __launch_bounds__(256) void hs_fin(
    const float2* __restrict__ partials, int nparts, float* __restrict__ out)
{
    double b = 0.0, c = 0.0;
    for (int i = threadIdx.x; i < nparts; i += blockDim.x) {
        const float2 p = partials[i];
        b += (double)p.x;
        c += (double)p.y;
    }
    __shared__ double sb[256], sc[256];
    sb[threadIdx.x] = b; sc[threadIdx.x] = c;
    __syncthreads();
    for (int s = 128; s > 0; s >>= 1) {
        if (threadIdx.x < s) {
            sb[threadIdx.x] += sb[threadIdx.x + s];
            sc[threadIdx.x] += sc[threadIdx.x + s];
        }
        __syncthreads();
    }
    if (threadIdx.x == 0) out[0] = (float)(sb[0] / sc[0]);
}

extern "C" void kernel_launch(void* const* d_in, const int* in_sizes, int n_in,
                              void* d_out, int out_size, void* d_ws, size_t ws_size,
                              hipStream_t stream) {
    const float* emb        = (const float*)d_in[0];
    const float* fc         = (const float*)d_in[1];
    const int*   target     = (const int*)d_in[2];
    const int*   path_idx   = (const int*)d_in[3];
    const float* path_codes = (const float*)d_in[4];
    const float* path_mask  = (const float*)d_in[5];

    const int N = in_sizes[2];
    const int C = in_sizes[1] / 256;          // V-1 fc rows
    const int V = C + 1;
    const int L = in_sizes[3] / V;

    float*  out      = (float*)d_out;
    float2* partials = (float2*)d_ws;         // [nblocks] at ws+0

    const int block = 256;
    int nblocks = (N + 3) / 4;                // 1 wave per row, 4 rows/block
    if (nblocks < 1) nblocks = 1;

    const size_t table_off   = 32768;         // past partials (16 KB) + pad
    const size_t table_bytes = (size_t)C * 256 * sizeof(unsigned short);
    const bool use_bf16 = (ws_size >= table_off + table_bytes) &&
                          ((size_t)nblocks * sizeof(float2) <= table_off);

    if (use_bf16) {
        unsigned short* fcb = (unsigned short*)((char*)d_ws + table_off);
        const int n8 = C * 32;                // groups of 8 floats (256/8 per row)
        fc_conv<<<2048, block, 0, stream>>>(fc, fcb, n8);
        hs_main_bf<<<nblocks, block, 0, stream>>>(emb, fcb, target, path_idx,
                                                  path_codes, path_mask,
                                                  partials, N, L);
    } else {
        if ((size_t)nblocks * sizeof(float2) > ws_size)
            nblocks = (int)(ws_size / sizeof(float2));
        hs_main_f32<<<nblocks, block, 0, stream>>>(emb, fc, target, path_idx,
                                                   path_codes, path_mask,
                                                   partials, N, L);
    }
    hs_fin<<<1, block, 0, stream>>>(partials, nblocks, out);
}

// Round 10
// 27.042 us; speedup vs baseline: 1.2113x; 1.2113x over previous
//
#include <hip/hip_runtime.h>

#define LD4(p) (*reinterpret_cast<const float4*>(p))

__device__ __forceinline__ float dot16(float4 e0, float4 e1, float4 e2, float4 e3,
                                       float4 w0, float4 w1, float4 w2, float4 w3) {
    return e0.x*w0.x + e0.y*w0.y + e0.z*w0.z + e0.w*w0.w
         + e1.x*w1.x + e1.y*w1.y + e1.z*w1.z + e1.w*w1.w
         + e2.x*w2.x + e2.y*w2.y + e2.z*w2.z + e2.w*w2.w
         + e3.x*w3.x + e3.y*w3.y + e3.z*w3.z + e3.w*w3.w;
}

__device__ __forceinline__ float red16(float q) {
    q += __shfl_xor(q, 1, 16);
    q += __shfl_xor(q, 2, 16);
    q += __shfl_xor(q, 4, 16);
    q += __shfl_xor(q, 8, 16);
    return q;   // all 16 lanes of the group hold the group's sum
}

__device__ __forceinline__ float bce_term(float q, float y, float m) {
    return m * (fmaxf(q, 0.0f) - q * y + __logf(1.0f + __expf(-fabsf(q))));
}

// One wave per row; 4 groups of 16 lanes split the path. Per outer iteration,
// ALL 16 path entries' gathers (4 nodes/group x 4 float4/lane = 16 float4)
// are issued in ONE burst -> one memory stall per typical row (plen<=16)
// instead of two (R8). ~64 data VGPRs by design.
__global__ __launch_bounds__(256) void hs_main(
    const float* __restrict__ emb,        // [N, 256]
    const float* __restrict__ fc,         // [V-1, 256]
    const int*   __restrict__ target,     // [N]
    const int*   __restrict__ path_idx,   // [V, L]
    const float* __restrict__ path_codes, // [V, L]
    const float* __restrict__ path_mask,  // [V, L]
    float2* __restrict__ partials,        // [gridDim.x]
    int N, int L)
{
    const int lane = threadIdx.x & 63;
    const int g    = lane >> 4;           // group 0..3
    const int li   = lane & 15;           // lane in group
    const int wid  = threadIdx.x >> 6;
    const int gwave  = blockIdx.x * (blockDim.x >> 6) + wid;
    const int nwaves = gridDim.x * (blockDim.x >> 6);

    float bce_acc = 0.0f;   // per-lane copy of its group's sum
    float cnt_acc = 0.0f;   // wave-uniform

    for (int row = gwave; row < N; row += nwaves) {
        const float* erow = emb + (size_t)row * 256 + li * 16;
        const float4 e0 = LD4(erow), e1 = LD4(erow + 4),
                     e2 = LD4(erow + 8), e3 = LD4(erow + 12);
        const int t = target[row];

        // path metadata: lane l holds entry l (coalesced); padded entries 0
        int pi = 0; float pc = 0.0f, pm = 0.0f;
        if (lane < L) {
            const size_t off = (size_t)t * L + lane;
            pi = path_idx[off];
            pc = path_codes[off];
            pm = path_mask[off];
        }
        const unsigned long long bal = __ballot(pm != 0.0f);
        const int plen = __popcll(bal);   // prefix mask, plen <= 64
        cnt_acc += (float)plen;

        for (int j16 = 0; j16 < plen; j16 += 16) {
            // entry indices for this group: j16 + 4k + g, k=0..3  (<= 63 always)
            const int i0 = j16 + g;
            const int i1 = j16 + 4  + g;
            const int i2 = j16 + 8  + g;
            const int i3 = j16 + 12 + g;
            const int n0 = __shfl(pi, i0, 64);
            const int n1 = __shfl(pi, i1, 64);
            const int n2 = __shfl(pi, i2, 64);
            const int n3 = __shfl(pi, i3, 64);
            const float* p0 = fc + ((size_t)n0 << 8) + li * 16;
            const float* p1 = fc + ((size_t)n1 << 8) + li * 16;
            const float* p2 = fc + ((size_t)n2 << 8) + li * 16;
            const float* p3 = fc + ((size_t)n3 << 8) + li * 16;
            // --- single burst: 16 independent float4 loads ---
            const float4 a0 = LD4(p0), a1 = LD4(p0+4), a2 = LD4(p0+8), a3 = LD4(p0+12);
            const float4 b0 = LD4(p1), b1 = LD4(p1+4), b2 = LD4(p1+8), b3 = LD4(p1+12);
            const float4 c0 = LD4(p2), c1 = LD4(p2+4), c2 = LD4(p2+8), c3 = LD4(p2+12);
            const float4 d0 = LD4(p3), d1 = LD4(p3+4), d2 = LD4(p3+8), d3 = LD4(p3+12);
            // broadcast codes while loads are in flight
            const float y0 = __shfl(pc, i0, 64);
            const float y1 = __shfl(pc, i1, 64);
            const float y2 = __shfl(pc, i2, 64);
            const float y3 = __shfl(pc, i3, 64);
            const float m0 = (i0 < plen) ? 1.0f : 0.0f;
            const float m1 = (i1 < plen) ? 1.0f : 0.0f;
            const float m2 = (i2 < plen) ? 1.0f : 0.0f;
            const float m3 = (i3 < plen) ? 1.0f : 0.0f;

            float q0 = dot16(e0, e1, e2, e3, a0, a1, a2, a3);
            float q1 = dot16(e0, e1, e2, e3, b0, b1, b2, b3);
            float q2 = dot16(e0, e1, e2, e3, c0, c1, c2, c3);
            float q3 = dot16(e0, e1, e2, e3, d0, d1, d2, d3);
            q0 = red16(q0); q1 = red16(q1); q2 = red16(q2); q3 = red16(q3);

            bce_acc += bce_term(q0, y0, m0);
            bce_acc += bce_term(q1, y1, m1);
            bce_acc += bce_term(q2, y2, m2);
            bce_acc += bce_term(q3, y3, m3);
        }
    }

    // sum the 4 groups (each lane holds its group's total)
    bce_acc += __shfl_xor(bce_acc, 16, 64);
    bce_acc += __shfl_xor(bce_acc, 32, 64);

    __shared__ float s_b[4], s_c[4];
    if (lane == 0) { s_b[wid] = bce_acc; s_c[wid] = cnt_acc; }
    __syncthreads();
    if (threadIdx.x == 0) {
        const int nw = blockDim.x >> 6;
        float b = 0.0f, c = 0.0f;
        for (int i = 0; i < nw; ++i) { b += s_b[i]; c += s_c[i]; }
        partials[blockIdx.x] = make_float2(b, c);
    }
}

__global__ __launch_bounds__(256) void hs_fin(
    const float2* __restrict__ partials, int nparts, float* __restrict__ out)
{
    double b = 0.0, c = 0.0;
    for (int i = threadIdx.x; i < nparts; i += blockDim.x) {
        const float2 p = partials[i];
        b += (double)p.x;
        c += (double)p.y;
    }
    __shared__ double sb[256], sc[256];
    sb[threadIdx.x] = b; sc[threadIdx.x] = c;
    __syncthreads();
    for (int s = 128; s > 0; s >>= 1) {
        if (threadIdx.x < s) {
            sb[threadIdx.x] += sb[threadIdx.x + s];
            sc[threadIdx.x] += sc[threadIdx.x + s];
        }
        __syncthreads();
    }
    if (threadIdx.x == 0) out[0] = (float)(sb[0] / sc[0]);
}

extern "C" void kernel_launch(void* const* d_in, const int* in_sizes, int n_in,
                              void* d_out, int out_size, void* d_ws, size_t ws_size,
                              hipStream_t stream) {
    const float* emb        = (const float*)d_in[0];
    const float* fc         = (const float*)d_in[1];
    const int*   target     = (const int*)d_in[2];
    const int*   path_idx   = (const int*)d_in[3];
    const float* path_codes = (const float*)d_in[4];
    const float* path_mask  = (const float*)d_in[5];

    const int N = in_sizes[2];
    const int V = in_sizes[1] / 256 + 1;
    const int L = in_sizes[3] / V;

    float2* partials = (float2*)d_ws;
    float*  out      = (float*)d_out;

    const int block = 256;                 // 4 waves/block, 1 row per wave
    int nblocks = (N + 3) / 4;             // 2048 blocks -> 8192 waves
    if (nblocks < 1) nblocks = 1;
    if ((size_t)nblocks * sizeof(float2) > ws_size)
        nblocks = (int)(ws_size / sizeof(float2));

    hs_main<<<nblocks, block, 0, stream>>>(emb, fc, target, path_idx, path_codes,
                                           path_mask, partials, N, L);
    hs_fin<<<1, block, 0, stream>>>(partials, nblocks, out);
}